// Round 3
// baseline (164.905 us; speedup 1.0000x reference)
//
#include <hip/hip_runtime.h>

#define NROWS 4096
#define NCOLS 4096
#define TAU 0.95f
#define MARGIN 1.0f
#define INV_TAU (1.0f / TAU)
#define LN2F 0.69314718056f

// R4 (resubmit; previous bench died on container-acquire, kernel never ran):
// one WAVE per row (was: one 4-wave block per row with 2 barriers).
// Rationale: R2/R3 showed dur invariant (~43.5us) across per-thread code and
// coalescing changes, with HBM 19%, VALU 30%, occupancy 55% -- nothing
// saturated => phase-convoy: block-wide barriers synchronized all resident
// waves into load-all/compute-all phases, draining the memory pipe each phase.
// The loss is separable: row_loss = -(sum log y) / norm, norm = f(labels
// only), so y never meets the scan. One wave owns a row: labels compressed
// to a 64-bit mask on arrival (2 VGPRs), one 6-step shfl scan, y streamed
// independently. No __syncthreads, no LDS. Grid 1024x256 = whole grid
// resident (16 waves/CU = the CU's 16 rows) -> memory pipe always fed.
__global__ __launch_bounds__(256, 4) void attncut_kernel(
    const float* __restrict__ cut_y, const int* __restrict__ cut_label,
    float* __restrict__ partials) {
  const int t = threadIdx.x;
  const int lane = t & 63;
  const int wid = t >> 6;
  const int row = (blockIdx.x << 2) | wid;  // 4 independent waves per block

  const size_t rbase = (size_t)row * NCOLS;
  // Lane l owns elements [l*64, l*64+64): 16 int4 + 16 float4 groups.
  const int4* lb = (const int4*)(cut_label + rbase) + lane * 16;
  const float4* yb = (const float4*)(cut_y + rbase) + lane * 16;

  // ---- Phase 1: labels -> 64-bit presence mask (labels are 0/1). ----
  unsigned int blo = 0u, bhi = 0u;
#pragma unroll
  for (int j = 0; j < 8; ++j) {
    const int4 L = lb[j];
    const unsigned int nib =
        (unsigned int)(L.x | (L.y << 1) | (L.z << 2) | (L.w << 3));
    blo |= nib << (4 * j);
  }
#pragma unroll
  for (int j = 0; j < 8; ++j) {
    const int4 L = lb[j + 8];
    const unsigned int nib =
        (unsigned int)(L.x | (L.y << 1) | (L.z << 2) | (L.w << 3));
    bhi |= nib << (4 * j);
  }
  const int lsum = __popc(blo) + __popc(bhi);

  // ---- Phase 2: y stream -> sum of log2 (independent of labels/scan). ----
  float l2 = 0.f;
#pragma unroll
  for (int j = 0; j < 16; ++j) {
    const float4 v = yb[j];
    // y in (1e-4, 1]: product of 4 in (1e-16, 1], safe f32; 1 v_log per 4.
    l2 += __log2f((v.x * v.y) * (v.z * v.w));
  }

  // ---- Phase 3: wave-inclusive scan of per-lane label sums. ----
  int x = lsum;
#pragma unroll
  for (int off = 1; off < 64; off <<= 1) {
    const int v = __shfl_up(x, off, 64);
    if (lane >= off) x += v;
  }
  const int Ttot = __shfl(x, 63, 64);  // row total
  const float Tf = (float)Ttot;
  float cf = (float)(x - lsum);  // exclusive prefix count for this lane

  // ---- Phase 4: walk 64 bits; na += exp(r/tau), r = 2c/(k+T). ----
  const float kb = (float)(lane * 64) + Tf;  // denom = kb + (j+1)
  float na = 0.f;
#pragma unroll
  for (int j = 0; j < 32; ++j) {
    cf += (float)((blo >> j) & 1u);
    const float r =
        (cf > 0.f) ? __fdividef(2.0f * cf, kb + (float)(j + 1)) : 0.f;
    na += __expf(r * INV_TAU);
  }
#pragma unroll
  for (int j = 0; j < 32; ++j) {
    cf += (float)((bhi >> j) & 1u);
    const float r =
        (cf > 0.f) ? __fdividef(2.0f * cf, kb + (float)(j + 33)) : 0.f;
    na += __expf(r * INV_TAU);
  }

  // ---- Phase 5: wave reduction (no LDS, no barrier). ----
#pragma unroll
  for (int off = 32; off > 0; off >>= 1) {
    na += __shfl_down(na, off, 64);
    l2 += __shfl_down(l2, off, 64);
  }
  if (lane == 0) {
    // norm = na (sum over the row of exp(r/tau)); ls = sum ln(y).
    partials[row] = -(l2 * LN2F) / (na * (float)NROWS);
  }
}

// Kernel 2 (single block): sum the 4096 per-row partials + rerank hinge loss.
__global__ __launch_bounds__(256) void finish_kernel(
    const float* __restrict__ partials, const float* __restrict__ rerank_y,
    float* __restrict__ out) {
  const int t = threadIdx.x;
  const int lane = t & 63, wid = t >> 6;

  float acc = 0.f;
  const float4* p4 = (const float4*)partials;  // 4096 floats = 1024 float4
#pragma unroll
  for (int i = 0; i < 4; ++i) {
    float4 v = p4[t + 256 * i];
    acc += (v.x + v.y) + (v.z + v.w);
  }

  float racc = 0.f;
  const float4* y4 = (const float4*)rerank_y;  // 8192 floats; float4 = 2 pairs
#pragma unroll
  for (int i = 0; i < 8; ++i) {
    float4 v = y4[t + 256 * i];
    racc += fmaxf(0.f, MARGIN - (v.x - v.y));
    racc += fmaxf(0.f, MARGIN - (v.z - v.w));
  }
  acc += racc * (1.0f / 4096.0f);

#pragma unroll
  for (int off = 32; off > 0; off >>= 1) acc += __shfl_down(acc, off, 64);
  __shared__ float ws[4];
  if (lane == 0) ws[wid] = acc;
  __syncthreads();
  if (t == 0) out[0] = (ws[0] + ws[1]) + (ws[2] + ws[3]);
}

extern "C" void kernel_launch(void* const* d_in, const int* in_sizes, int n_in,
                              void* d_out, int out_size, void* d_ws, size_t ws_size,
                              hipStream_t stream) {
  const float* rerank_y = (const float*)d_in[0];   // (8192, 1) f32
  const float* cut_y = (const float*)d_in[1];      // (4096, 4096, 1) f32
  // d_in[2] = rerank_label, unused by the reference loss
  const int* cut_label = (const int*)d_in[3];      // (4096, 4096) i32
  float* out = (float*)d_out;                      // scalar f32
  float* partials = (float*)d_ws;                  // 4096 f32 (16 KB scratch)

  attncut_kernel<<<NROWS / 4, 256, 0, stream>>>(cut_y, cut_label, partials);
  finish_kernel<<<1, 256, 0, stream>>>(partials, rerank_y, out);
}

// Round 4
// 158.642 us; speedup vs baseline: 1.0395x; 1.0395x over previous
//
#include <hip/hip_runtime.h>

#define NROWS 4096
#define NCOLS 4096
#define TAU 0.95f
#define MARGIN 1.0f
#define INV_TAU (1.0f / TAU)
#define LN2F 0.69314718056f

// R5: split the separable loss into two pure-stream kernels.
// row_loss = -(sum ln y)/norm, norm = f(labels only) => y-stream and
// label-stream never meet element-wise. R1-R4 evidence: dur tracks total
// traffic at ~2.4 TB/s regardless of structure; mixed-stream kernels never
// exceeded ~1.8 TB/s HBM. Kernel A is a textbook streaming reduce (should
// hit 5-6 TB/s); its rate is the diagnostic. Kernel B walks labels with a
// ballot/mbcnt cross-lane prefix (no scan, no LDS, no barriers).

__device__ __forceinline__ int mbcnt64(unsigned long long m) {
  return __builtin_amdgcn_mbcnt_hi(
      (unsigned int)(m >> 32),
      __builtin_amdgcn_mbcnt_lo((unsigned int)m, 0));
}

// Kernel A: per-row sum of ln(y). One wave per row; 16 lane-contiguous
// float4 loads; log2 of product-of-4 (y in (1e-4,1] -> product >= 1e-16,
// safe in f32); wave-reduce; lane 0 stores sum(ln y) to partials[row].
__global__ __launch_bounds__(256, 4) void ylog_kernel(
    const float* __restrict__ cut_y, float* __restrict__ partials) {
  const int t = threadIdx.x;
  const int lane = t & 63;
  const int wid = t >> 6;
  const int row = (blockIdx.x << 2) | wid;
  const float4* yb = (const float4*)(cut_y + (size_t)row * NCOLS);

  float l2 = 0.f;
#pragma unroll
  for (int j = 0; j < 16; ++j) {
    const float4 v = yb[lane + 64 * j];
    l2 += __log2f((v.x * v.y) * (v.z * v.w));
  }
#pragma unroll
  for (int off = 32; off > 0; off >>= 1) l2 += __shfl_down(l2, off, 64);
  if (lane == 0) partials[row] = l2 * LN2F;
}

// Kernel B: per-row norm from labels; finishes the row loss in place.
// Element (segment j, lane, e) is row element (64j+lane)*4 + e: every int4
// load is lane-contiguous. Labels packed to 64 bits/lane (bit 4j+e). Row
// total T via popc + wave-reduce. Per segment, cross-lane exclusive counts
// come from 4 ballots + mbcnt (count of 1s in lower lanes, all positions).
__global__ __launch_bounds__(256, 4) void norm_kernel(
    const int* __restrict__ cut_label, float* __restrict__ partials) {
  const int t = threadIdx.x;
  const int lane = t & 63;
  const int wid = t >> 6;
  const int row = (blockIdx.x << 2) | wid;
  const int4* lb = (const int4*)(cut_label + (size_t)row * NCOLS);

  // Pass 1: 16 coalesced int4 loads -> 64-bit presence mask.
  unsigned int blo = 0u, bhi = 0u;
#pragma unroll
  for (int j = 0; j < 8; ++j) {
    const int4 L = lb[lane + 64 * j];
    blo |= (unsigned int)(L.x | (L.y << 1) | (L.z << 2) | (L.w << 3))
           << (4 * j);
  }
#pragma unroll
  for (int j = 0; j < 8; ++j) {
    const int4 L = lb[lane + 64 * (j + 8)];
    bhi |= (unsigned int)(L.x | (L.y << 1) | (L.z << 2) | (L.w << 3))
           << (4 * j);
  }

  // Row total T.
  int ls = __popc(blo) + __popc(bhi);
#pragma unroll
  for (int off = 32; off > 0; off >>= 1) ls += __shfl_down(ls, off, 64);
  const float Tf = (float)__shfl(ls, 0, 64);

  // Pass 2: 16 segments of 256 elements (4/lane).
  float na = 0.f;  // sum exp(r/tau) over this lane's elements
  float Cf = 0.f;  // row count consumed by segments < j (wave-uniform)
#pragma unroll
  for (int j = 0; j < 16; ++j) {
    const unsigned int nib =
        ((j < 8) ? (blo >> (4 * j)) : (bhi >> (4 * (j - 8)))) & 0xFu;
    const unsigned long long b0 = __ballot(nib & 1u);
    const unsigned long long b1 = __ballot(nib & 2u);
    const unsigned long long b2 = __ballot(nib & 4u);
    const unsigned long long b3 = __ballot(nib & 8u);
    const int before = mbcnt64(b0) + mbcnt64(b1) + mbcnt64(b2) + mbcnt64(b3);

    float c = Cf + (float)before;            // exclusive count before my elems
    const float kb = (float)(4 * (64 * j + lane)) + Tf;  // denom = kb + (e+1)

    c += (float)(nib & 1u);
    na += __expf(((c > 0.f) ? __fdividef(2.0f * c, kb + 1.0f) : 0.f) * INV_TAU);
    c += (float)((nib >> 1) & 1u);
    na += __expf(((c > 0.f) ? __fdividef(2.0f * c, kb + 2.0f) : 0.f) * INV_TAU);
    c += (float)((nib >> 2) & 1u);
    na += __expf(((c > 0.f) ? __fdividef(2.0f * c, kb + 3.0f) : 0.f) * INV_TAU);
    c += (float)((nib >> 3) & 1u);
    na += __expf(((c > 0.f) ? __fdividef(2.0f * c, kb + 4.0f) : 0.f) * INV_TAU);

    Cf += (float)(__popcll(b0) + __popcll(b1) + __popcll(b2) + __popcll(b3));
  }

  // Wave reduction of na; lane 0 finishes the row in place.
#pragma unroll
  for (int off = 32; off > 0; off >>= 1) na += __shfl_down(na, off, 64);
  if (lane == 0) {
    const float lnsum = partials[row];  // written by ylog_kernel (same stream)
    partials[row] = -lnsum / (na * (float)NROWS);
  }
}

// Kernel 3 (single block): sum the 4096 per-row partials + rerank hinge loss.
__global__ __launch_bounds__(256) void finish_kernel(
    const float* __restrict__ partials, const float* __restrict__ rerank_y,
    float* __restrict__ out) {
  const int t = threadIdx.x;
  const int lane = t & 63, wid = t >> 6;

  float acc = 0.f;
  const float4* p4 = (const float4*)partials;  // 4096 floats = 1024 float4
#pragma unroll
  for (int i = 0; i < 4; ++i) {
    float4 v = p4[t + 256 * i];
    acc += (v.x + v.y) + (v.z + v.w);
  }

  float racc = 0.f;
  const float4* y4 = (const float4*)rerank_y;  // 8192 floats; float4 = 2 pairs
#pragma unroll
  for (int i = 0; i < 8; ++i) {
    float4 v = y4[t + 256 * i];
    racc += fmaxf(0.f, MARGIN - (v.x - v.y));
    racc += fmaxf(0.f, MARGIN - (v.z - v.w));
  }
  acc += racc * (1.0f / 4096.0f);

#pragma unroll
  for (int off = 32; off > 0; off >>= 1) acc += __shfl_down(acc, off, 64);
  __shared__ float ws[4];
  if (lane == 0) ws[wid] = acc;
  __syncthreads();
  if (t == 0) out[0] = (ws[0] + ws[1]) + (ws[2] + ws[3]);
}

extern "C" void kernel_launch(void* const* d_in, const int* in_sizes, int n_in,
                              void* d_out, int out_size, void* d_ws, size_t ws_size,
                              hipStream_t stream) {
  const float* rerank_y = (const float*)d_in[0];   // (8192, 1) f32
  const float* cut_y = (const float*)d_in[1];      // (4096, 4096, 1) f32
  // d_in[2] = rerank_label, unused by the reference loss
  const int* cut_label = (const int*)d_in[3];      // (4096, 4096) i32
  float* out = (float*)d_out;                      // scalar f32
  float* partials = (float*)d_ws;                  // 4096 f32 (16 KB scratch)

  ylog_kernel<<<NROWS / 4, 256, 0, stream>>>(cut_y, partials);
  norm_kernel<<<NROWS / 4, 256, 0, stream>>>(cut_label, partials);
  finish_kernel<<<1, 256, 0, stream>>>(partials, rerank_y, out);
}